// Round 1
// baseline (1158.933 us; speedup 1.0000x reference)
//
#include <hip/hip_runtime.h>

#define CAPACITY 2000000
#define DIM 128
#define BATCH 16384

// Phase A: segment_ids (sorted) -> per-bag start offsets offs[0..BATCH]
// offs[b] = first key index of bag b; offs[BATCH] = n. Empty bags get
// offs[b] == offs[b+1]. One thread per key position (plus one for i==n).
__global__ void seg_offsets_kernel(const int* __restrict__ seg, int n,
                                   int* __restrict__ offs) {
    int i = blockIdx.x * blockDim.x + threadIdx.x;
    if (i > n) return;
    int cur  = (i < n) ? seg[i]     : BATCH;
    int prev = (i > 0) ? seg[i - 1] : -1;
    // fill starts for every segment id in (prev, cur]
    for (int s = prev + 1; s <= cur; ++s) offs[s] = i;
}

// Phase B: one 64-lane wave per bag. Lane l accumulates dims [2l, 2l+1]
// as a float2. Row fetch = 64 lanes x 8 B = 512 B fully coalesced.
__global__ __launch_bounds__(256) void pool_kernel(
        const int*   __restrict__ keys,
        const float* __restrict__ weight,
        const int*   __restrict__ offs,
        float*       __restrict__ out) {
    int gtid = blockIdx.x * blockDim.x + threadIdx.x;
    int bag  = gtid >> 6;
    int lane = threadIdx.x & 63;
    if (bag >= BATCH) return;

    int s = offs[bag];
    int e = offs[bag + 1];

    const float2* __restrict__ w2 = (const float2*)weight;  // row r at r*64

    float2 acc = make_float2(0.0f, 0.0f);

    int k = s;
    // 8-wide unroll: 8 independent gathers in flight per wave.
    for (; k + 8 <= e; k += 8) {
        float2 v[8];
#pragma unroll
        for (int u = 0; u < 8; ++u) {
            int idx = keys[k + u] % CAPACITY;        // keys are nonnegative
            size_t row = (size_t)(idx + 1) * 64;     // +1: row 0 = miss sentinel
            v[u] = w2[row + lane];
        }
#pragma unroll
        for (int u = 0; u < 8; ++u) {
            acc.x += v[u].x;
            acc.y += v[u].y;
        }
    }
    // tail
    for (; k < e; ++k) {
        int idx = keys[k] % CAPACITY;
        size_t row = (size_t)(idx + 1) * 64;
        float2 v = w2[row + lane];
        acc.x += v.x;
        acc.y += v.y;
    }

    ((float2*)out)[(size_t)bag * 64 + lane] = acc;
}

extern "C" void kernel_launch(void* const* d_in, const int* in_sizes, int n_in,
                              void* d_out, int out_size, void* d_ws, size_t ws_size,
                              hipStream_t stream) {
    const int*   keys   = (const int*)d_in[0];
    const int*   seg    = (const int*)d_in[1];
    const float* weight = (const float*)d_in[2];
    float*       out    = (float*)d_out;
    int n = in_sizes[0];

    int* offs = (int*)d_ws;  // BATCH+1 ints = 64 KiB + 4 B, fits any ws

    {
        int threads = 256;
        int blocks  = (n + 1 + threads - 1) / threads;
        seg_offsets_kernel<<<blocks, threads, 0, stream>>>(seg, n, offs);
    }
    {
        int threads = 256;                       // 4 bags per block
        long total  = (long)BATCH * 64;
        int blocks  = (int)((total + threads - 1) / threads);
        pool_kernel<<<blocks, threads, 0, stream>>>(keys, weight, offs, out);
    }
}